// Round 8
// baseline (193.195 us; speedup 1.0000x reference)
//
#include <hip/hip_runtime.h>
#include <hip/hip_bf16.h>

#define B_  32
#define HW_ 4096
#define C_  256
#define S_LDS 40   // LDS row stride in ushorts (80B): 16B-aligned rows, b128 r/w conflict-light

using bf16x8 = __attribute__((ext_vector_type(8))) short;
using f32x4  = __attribute__((ext_vector_type(4))) float;
using u32x4  = __attribute__((ext_vector_type(4))) uint;

__device__ __forceinline__ ushort f2bf_rn(float x) {
    uint u = __builtin_bit_cast(uint, x);
    u += 0x7FFFu + ((u >> 16) & 1u);
    return (ushort)(u >> 16);
}
__device__ __forceinline__ uint pk_bf2(float a, float b) {   // RN pack (K2 only)
    return ((uint)f2bf_rn(b) << 16) | (uint)f2bf_rn(a);
}
// 1-instr RTZ pack of two floats' top-16 bits: {bf16_rtz(x1), bf16_rtz(x0)}
__device__ __forceinline__ uint pk_rtz(float x0, float x1) {
    return __builtin_amdgcn_perm(__builtin_bit_cast(uint, x1),
                                 __builtin_bit_cast(uint, x0), 0x07060302u);
}
// RTZ split: x = hi + lo, hi = truncate-to-bf16, |lo| <= 2^-8|x|
__device__ __forceinline__ void split2_rtz(float x0, float x1, uint& hi2, uint& lo2) {
    uint u0 = __builtin_bit_cast(uint, x0), u1 = __builtin_bit_cast(uint, x1);
    hi2 = __builtin_amdgcn_perm(u1, u0, 0x07060302u);
    float h0 = __builtin_bit_cast(float, u0 & 0xFFFF0000u);
    float h1 = __builtin_bit_cast(float, u1 & 0xFFFF0000u);
    lo2 = pk_rtz(x0 - h0, x1 - h1);
}

// ---------------------------------------------------------------------------
// K1: scores[b,q,k] = sum_hw Q[b,hw,q]*K[b,hw,k] via 3-term bf16 RTZ split.
// Tile 128(q) x 128(k), split-K=8. 256-thread blocks (4 waves, 2x2 grid of
// 64x64 wave tiles) -> 4 INDEPENDENT blocks/CU (barrier groups stagger and
// cover each other's load/convert/barrier stalls). bf16 split done ONCE per
// element at staging (stage-side), hi/lo tiles in LDS, b128 reads.
// grid 1024 = b(32) * tm(2) * tn(2) * s(8).
// ---------------------------------------------------------------------------
__global__ __launch_bounds__(256, 4) void scores_kernel(const float* __restrict__ qg,
                                                        const float* __restrict__ kg,
                                                        float* __restrict__ scores) {
    int x  = blockIdx.x;
    int s  = x & 7;
    int tn = (x >> 3) & 1;
    int tm = (x >> 4) & 1;
    int b  = x >> 5;

    __shared__ __align__(16) ushort Qhi[128 * S_LDS], Qlo[128 * S_LDS];
    __shared__ __align__(16) ushort Khi[128 * S_LDS], Klo[128 * S_LDS];

    int tid = threadIdx.x, lane = tid & 63, w = tid >> 6;
    int m0 = (w >> 1) * 64;
    int n0 = (w & 1) * 64;
    int g = lane >> 4, r16 = lane & 15;

    int cq = tid & 127;          // staging channel (same for Q and K)
    int hq = (tid >> 7) * 16;    // hw offset {0,16}, 16 values per thread

    const float* qcol = qg + (size_t)b * HW_ * C_ + tm * 128 + cq;
    const float* kcol = kg + (size_t)b * HW_ * C_ + tn * 128 + cq;

    f32x4 acc[4][4];
#pragma unroll
    for (int i = 0; i < 4; ++i)
#pragma unroll
        for (int j = 0; j < 4; ++j) acc[i][j] = (f32x4){0.f, 0.f, 0.f, 0.f};

    for (int it = 0; it < 16; ++it) {
        int hw0 = s * 512 + it * 32 + hq;

        // ---- global loads (32 dwords, independent -> compiler hoists & overlaps)
        float qv[16], kv[16];
        const float* qp = qcol + (size_t)hw0 * C_;
        const float* kp = kcol + (size_t)hw0 * C_;
#pragma unroll
        for (int j = 0; j < 16; ++j) qv[j] = qp[(size_t)j * C_];
#pragma unroll
        for (int j = 0; j < 16; ++j) kv[j] = kp[(size_t)j * C_];

        __syncthreads();   // previous iter's MFMA reads done before overwrite

        // ---- stage-side split (once per element), b128 stores
        {
            uint h[8], l[8];
#pragma unroll
            for (int p = 0; p < 8; ++p) split2_rtz(qv[2 * p], qv[2 * p + 1], h[p], l[p]);
            int base = cq * S_LDS + hq;
            *reinterpret_cast<u32x4*>(&Qhi[base])     = (u32x4){h[0], h[1], h[2], h[3]};
            *reinterpret_cast<u32x4*>(&Qhi[base + 8]) = (u32x4){h[4], h[5], h[6], h[7]};
            *reinterpret_cast<u32x4*>(&Qlo[base])     = (u32x4){l[0], l[1], l[2], l[3]};
            *reinterpret_cast<u32x4*>(&Qlo[base + 8]) = (u32x4){l[4], l[5], l[6], l[7]};
#pragma unroll
            for (int p = 0; p < 8; ++p) split2_rtz(kv[2 * p], kv[2 * p + 1], h[p], l[p]);
            *reinterpret_cast<u32x4*>(&Khi[base])     = (u32x4){h[0], h[1], h[2], h[3]};
            *reinterpret_cast<u32x4*>(&Khi[base + 8]) = (u32x4){h[4], h[5], h[6], h[7]};
            *reinterpret_cast<u32x4*>(&Klo[base])     = (u32x4){l[0], l[1], l[2], l[3]};
            *reinterpret_cast<u32x4*>(&Klo[base + 8]) = (u32x4){l[4], l[5], l[6], l[7]};
        }
        __syncthreads();

        // ---- MFMA phase (A-resident, B re-read per ni). T5 setprio around cluster.
        __builtin_amdgcn_s_setprio(1);
        bf16x8 ahi[4], alo[4];
#pragma unroll
        for (int mi = 0; mi < 4; ++mi) {
            int off = (m0 + mi * 16 + r16) * S_LDS + g * 8;
            ahi[mi] = *reinterpret_cast<const bf16x8*>(&Qhi[off]);
            alo[mi] = *reinterpret_cast<const bf16x8*>(&Qlo[off]);
        }
#pragma unroll
        for (int ni = 0; ni < 4; ++ni) {
            int off = (n0 + ni * 16 + r16) * S_LDS + g * 8;
            bf16x8 bhi = *reinterpret_cast<const bf16x8*>(&Khi[off]);
            bf16x8 blo = *reinterpret_cast<const bf16x8*>(&Klo[off]);
#pragma unroll
            for (int mi = 0; mi < 4; ++mi) {
                acc[mi][ni] = __builtin_amdgcn_mfma_f32_16x16x32_bf16(ahi[mi], bhi, acc[mi][ni], 0, 0, 0);
                acc[mi][ni] = __builtin_amdgcn_mfma_f32_16x16x32_bf16(ahi[mi], blo, acc[mi][ni], 0, 0, 0);
                acc[mi][ni] = __builtin_amdgcn_mfma_f32_16x16x32_bf16(alo[mi], bhi, acc[mi][ni], 0, 0, 0);
            }
        }
        __builtin_amdgcn_s_setprio(0);
    }

    // ---- epilogue: C/D layout col=lane&15, row=(lane>>4)*4+reg (m89-verified)
#pragma unroll
    for (int mi = 0; mi < 4; ++mi)
#pragma unroll
        for (int ni = 0; ni < 4; ++ni)
#pragma unroll
            for (int r = 0; r < 4; ++r) {
                int qrow = tm * 128 + m0 + mi * 16 + g * 4 + r;
                int kc   = tn * 128 + n0 + ni * 16 + r16;
                atomicAdd(&scores[((size_t)b * 256 + qrow) * 256 + kc], acc[mi][ni][r]);
            }
}

// ---------------------------------------------------------------------------
// K2: row softmax over k (256), one wave per row; attn stored as bf16 (RN).
// ---------------------------------------------------------------------------
__global__ __launch_bounds__(256) void softmax_kernel(const float* __restrict__ scores,
                                                      ushort* __restrict__ attn) {
    int wid  = blockIdx.x * 4 + (threadIdx.x >> 6);
    int lane = threadIdx.x & 63;
    const float4 v = *reinterpret_cast<const float4*>(scores + (size_t)wid * 256 + lane * 4);
    float m = fmaxf(fmaxf(v.x, v.y), fmaxf(v.z, v.w));
#pragma unroll
    for (int off = 32; off; off >>= 1) m = fmaxf(m, __shfl_xor(m, off, 64));
    float e0 = __expf(v.x - m), e1 = __expf(v.y - m), e2 = __expf(v.z - m), e3 = __expf(v.w - m);
    float ssum = e0 + e1 + e2 + e3;
#pragma unroll
    for (int off = 32; off; off >>= 1) ssum += __shfl_xor(ssum, off, 64);
    float inv = 1.0f / ssum;
    uint2 o;
    o.x = pk_bf2(e0 * inv, e1 * inv);
    o.y = pk_bf2(e2 * inv, e3 * inv);
    *reinterpret_cast<uint2*>(attn + (size_t)wid * 256 + lane * 4) = o;
}

// ---------------------------------------------------------------------------
// K3: out[b,q,hw] = sum_k attn[b,q,k] * V[b,hw,k].  M=256 x N=64 tile, K=256
// in 8 steps of 32. V tile staged ONCE per block into LDS (fp32, XOR-swizzled
// 16B slots), double-buffered with T14 async-stage: issue ks+1 loads ->
// compute ks from LDS -> write ks+1 -> barrier. Waves read shared V from LDS.
// grid 2048 = b(32) * hw-tile(64); block 256 (4 waves, each 64q x 64hw).
// ---------------------------------------------------------------------------
__global__ __launch_bounds__(256, 4) void pv_kernel(const ushort* __restrict__ attn,
                                                    const float* __restrict__ vg,
                                                    float* __restrict__ out) {
    int b   = blockIdx.x >> 6;
    int hw0 = (blockIdx.x & 63) * 64;
    int tid = threadIdx.x, lane = tid & 63, w = tid >> 6;
    int m0  = w * 64;
    int g   = lane >> 4, r16 = lane & 15;

    __shared__ __align__(16) float Vt[2 * 64 * 32];   // [buf][hw 64][k 32], swizzled

    int srow = tid >> 2;
    int sslot = (tid & 3) * 2;
    int wi0 = srow * 32 + ((sslot ^ (srow & 7)) * 4);
    int wi1 = srow * 32 + (((sslot + 1) ^ (srow & 7)) * 4);
    const float* vstage = vg + ((size_t)(b * HW_ + hw0 + srow)) * C_ + sslot * 4;

    const ushort* abase = attn + (size_t)b * 256 * 256 + g * 8;

    f32x4 acc[4][4];
#pragma unroll
    for (int i = 0; i < 4; ++i)
#pragma unroll
        for (int j = 0; j < 4; ++j) acc[i][j] = (f32x4){0.f, 0.f, 0.f, 0.f};

    {
        f32x4 p0 = *reinterpret_cast<const f32x4*>(vstage);
        f32x4 p1 = *reinterpret_cast<const f32x4*>(vstage + 4);
        *reinterpret_cast<f32x4*>(&Vt[wi0]) = p0;
        *reinterpret_cast<f32x4*>(&Vt[wi1]) = p1;
    }
    __syncthreads();

    for (int p = 0; p < 8; ++p) {
        float* rbuf = &Vt[(p & 1) * 64 * 32];
        float* wbuf = &Vt[((p + 1) & 1) * 64 * 32];

        f32x4 n0v, n1v;
        if (p < 7) {
            n0v = *reinterpret_cast<const f32x4*>(vstage + (p + 1) * 32);
            n1v = *reinterpret_cast<const f32x4*>(vstage + (p + 1) * 32 + 4);
        }

        int k0 = p * 32;
        bf16x8 a[4];
#pragma unroll
        for (int mi = 0; mi < 4; ++mi)
            a[mi] = *reinterpret_cast<const bf16x8*>(abase + (size_t)(m0 + mi * 16 + r16) * 256 + k0);

#pragma unroll
        for (int ni = 0; ni < 4; ++ni) {
            int row = ni * 16 + r16, key = row & 7;
            f32x4 f0 = *reinterpret_cast<const f32x4*>(&rbuf[row * 32 + (((2 * g)     ^ key) * 4)]);
            f32x4 f1 = *reinterpret_cast<const f32x4*>(&rbuf[row * 32 + (((2 * g + 1) ^ key) * 4)]);
            bf16x8 bf = __builtin_bit_cast(bf16x8, (u32x4){
                pk_rtz(f0[0], f0[1]), pk_rtz(f0[2], f0[3]),
                pk_rtz(f1[0], f1[1]), pk_rtz(f1[2], f1[3])});
#pragma unroll
            for (int mi = 0; mi < 4; ++mi)
                acc[mi][ni] = __builtin_amdgcn_mfma_f32_16x16x32_bf16(a[mi], bf, acc[mi][ni], 0, 0, 0);
        }

        if (p < 7) {
            *reinterpret_cast<f32x4*>(&wbuf[wi0]) = n0v;
            *reinterpret_cast<f32x4*>(&wbuf[wi1]) = n1v;
            __syncthreads();
        }
    }

#pragma unroll
    for (int mi = 0; mi < 4; ++mi)
#pragma unroll
        for (int ni = 0; ni < 4; ++ni)
#pragma unroll
            for (int r = 0; r < 4; ++r) {
                int qrow = m0 + mi * 16 + g * 4 + r;
                int hw   = hw0 + ni * 16 + r16;
                out[((size_t)b * 256 + qrow) * 4096 + hw] = acc[mi][ni][r];
            }
}

extern "C" void kernel_launch(void* const* d_in, const int* in_sizes, int n_in,
                              void* d_out, int out_size, void* d_ws, size_t ws_size,
                              hipStream_t stream) {
    const float* q = (const float*)d_in[0];
    const float* k = (const float*)d_in[1];
    const float* v = (const float*)d_in[2];
    float* out = (float*)d_out;

    float*  scores = (float*)d_ws;
    ushort* attn   = (ushort*)((char*)d_ws + (size_t)B_ * 256 * 256 * 4);

    (void)hipMemsetAsync(d_ws, 0, (size_t)B_ * 256 * 256 * 4, stream);
    scores_kernel<<<1024, 256, 0, stream>>>(q, k, scores);
    softmax_kernel<<<2048, 256, 0, stream>>>(scores, attn);
    pv_kernel<<<2048, 256, 0, stream>>>(attn, v, out);
}